// Round 10
// baseline (285.699 us; speedup 1.0000x reference)
//
#include <hip/hip_runtime.h>
#include <hip/hip_bf16.h>
#include <math.h>

// ---------------- problem constants ----------------
#define BB 262144
#define NST 20
#define RHc 0.006f            // R*H
#define BHc 0.01f             // B_DRIFT*H
#define SIGc 0.2f
#define CURTc 0.005f
#define DISCf 0.8869204367171575f   // exp(-0.12)

// ---------------- launch geometry ----------------
#define THB_SIM 512
#define NBLK_SIM 1024          // 256 paths per block (8 waves x 32)
#define H1_BLK 16
#define H1_THR 1024
#define W_BLK 256
#define W_THR 256

// ---------------- workspace layout (floats from ws base unless noted) ----------------
#define SIMP_OFF  BB                          // float[NBLK_SIM*5]
#define TAILP_OFF (SIMP_OFF + NBLK_SIM * 5)   // float[W_BLK*4]
#define ICTRL     (TAILP_OFF + W_BLK * 4)     // int region base
// ctrl ints:
#define H2_OFF 0                      // 4*2048
#define H3_OFF 8192                   // 4*1024
#define CNT_OFF 12288
#define ST_OFF  12296
#define SF_OFF  12320
#define ZTOT    12289
#define H1R_OFF 12352                 // 16 rows x 2048 ints (written AFTER sim)
// prep region OVERLAYS H1R (prep consumed by sim; H1R written by hist1 post-sim)
#define PREP_OFF (ICTRL + H1R_OFF)
// compact per-step layout (dwords): A2c0 256 | A2c1 128 | A3c0 40 | A3c1 20 | L1p 24 | pad 4
#define CSTR 472
#define HEADO (19 * CSTR)             // Wu0m[8], bu0m[8]
#define PREP_DW (HEADO + 16)          // 8984 dwords = 35.9 KB (fits H1R overlay 32768 ints)
#define PREP_I4 2246                  // ceil(PREP_DW/4)

// ---------------- types / helpers ----------------
typedef float f32x16 __attribute__((ext_vector_type(16)));
typedef short bf16x8 __attribute__((ext_vector_type(8)));
union F8  { int4 i; bf16x8 b; };
union BFR { unsigned u[4]; int4 i; bf16x8 b; };

__device__ __forceinline__ unsigned pkbf(float lo, float hi) {   // 1 VALU op
    unsigned r;
    asm("v_cvt_pk_bf16_f32 %0, %1, %2" : "=v"(r) : "v"(lo), "v"(hi));
    return r;
}
__device__ __forceinline__ float bflo(unsigned u) { return __uint_as_float(u << 16); }
__device__ __forceinline__ float bfhi(unsigned u) { return __uint_as_float(u & 0xffff0000u); }
__device__ __forceinline__ unsigned fkey(float f) {
    unsigned u = __float_as_uint(f);
    return (u & 0x80000000u) ? ~u : (u | 0x80000000u);
}
__device__ __forceinline__ float funkey(unsigned k) {
    return __uint_as_float((k & 0x80000000u) ? (k ^ 0x80000000u) : ~k);
}
__device__ __forceinline__ float wred(float v) {
#pragma unroll
    for (int o = 32; o > 0; o >>= 1) v += __shfl_down(v, o);
    return v;
}
__device__ __forceinline__ unsigned short f2bf(float f) {   // RNE
    unsigned u = __float_as_uint(f);
    unsigned r = u + 0x7fffu + ((u >> 16) & 1u);
    return (unsigned short)(r >> 16);
}
__device__ __forceinline__ int pk2(float lo, float hi) {
    return (int)(((unsigned)f2bf(hi) << 16) | f2bf(lo));
}

__global__ void zero_kernel(int* __restrict__ ctrl) {
    int i = blockIdx.x * blockDim.x + threadIdx.x;
    if (i < ZTOT) ctrl[i] = 0;
}

// ---------------- prep: compact MFMA fragment form ----------------
// k-slot labeling (32x32x16 bf16): lane l, dword v, half h:
//   k = 16c + 8*(v>>1) + 4*(l>>5) + 2*(v&1) + h ; A row / B col = l&31
// Bias fold: A k-slot 20 holds b2/b3; B k-slot 20 holds 1.0 for g1 lanes.
__global__ void prep_kernel(const float* __restrict__ Wu0, const float* __restrict__ bu0,
                            const float* __restrict__ W1, const float* __restrict__ b1,
                            const float* __restrict__ W2, const float* __restrict__ b2,
                            const float* __restrict__ W3, const float* __restrict__ b3,
                            float* __restrict__ prepF)
{
    const int s = blockIdx.x, tid = threadIdx.x;
    int* prepI = (int*)prepF;
    if (s < 19) {
        // A2c0: 256 dwords (lane l, v) — c=0, kb = 8*(v>>1)+4g+2*(v&1) (<=14)
        {
            int t = tid;  // 256 threads
            int l = t >> 2, v = t & 3, g = l >> 5, row = l & 31;
            int kb = 8 * (v >> 1) + 4 * g + 2 * (v & 1);
            float lo = (row < 20) ? W2[s * 400 + kb * 20 + row] : 0.f;
            float hi = (row < 20) ? W2[s * 400 + (kb + 1) * 20 + row] : 0.f;
            prepI[s * CSTR + t] = pk2(lo, hi);
        }
        // A2c1 compact: 128 dwords (lane l, vv) — kb = 16+4g+2vv
        if (tid < 128) {
            int l = tid >> 1, vv = tid & 1, g = l >> 5, row = l & 31;
            int kb = 16 + 4 * g + 2 * vv;
            float lo = 0.f, hi = 0.f;
            if (row < 20) {
                if (kb < 20)       lo = W2[s * 400 + kb * 20 + row];
                else if (kb == 20) lo = b2[s * 20 + row];
                if (kb + 1 < 20)   hi = W2[s * 400 + (kb + 1) * 20 + row];
            }
            prepI[s * CSTR + 256 + tid] = pk2(lo, hi);
        }
        // A3c0 compact: 40 dwords (e = g*5+row in 0..9, v)
        if (tid < 40) {
            int e = tid >> 2, v = tid & 3, g = e / 5, row = e % 5;
            int kb = 8 * (v >> 1) + 4 * g + 2 * (v & 1);
            float lo = W3[s * 100 + kb * 5 + row];
            float hi = W3[s * 100 + (kb + 1) * 5 + row];
            prepI[s * CSTR + 384 + tid] = pk2(lo, hi);
        }
        // A3c1 compact: 20 dwords (e, vv) — kb = 16+4g+2vv
        if (tid < 20) {
            int e = tid >> 1, vv = tid & 1, g = e / 5, row = e % 5;
            int kb = 16 + 4 * g + 2 * vv;
            float lo = 0.f, hi = 0.f;
            if (kb < 20)       lo = W3[s * 100 + kb * 5 + row];
            else if (kb == 20) lo = b3[s * 5 + row];
            if (kb + 1 < 20)   hi = W3[s * 100 + (kb + 1) * 5 + row];
            prepI[s * CSTR + 424 + tid] = pk2(lo, hi);
        }
        // L1p: 24 dwords (w lo, b hi), neuron order per B k-slot map
        if (tid < 24) {
            int g = tid / 12, j = tid % 12;
            int n = (j < 4) ? 4 * g + j : (j < 8) ? 8 + 4 * g + (j - 4) : 16 + 4 * g + (j - 8);
            unsigned w = 0, b = 0;
            if (n < 20) { w = f2bf(W1[s * 20 + n]); b = f2bf(b1[s * 20 + n]); }
            prepI[s * CSTR + 444 + tid] = (int)((b << 16) | w);
        }
        if (tid >= 24 && tid < 28) prepI[s * CSTR + 444 + tid] = 0;  // pad 468..471
    } else {
        if (tid < 8) {    // Wu0/bu0 mapped to alpha C-regs 0-3 per g (d = r + 4g)
            int g = tid >> 2, r = tid & 3, d = r + 4 * g;
            prepF[HEADO + tid]     = (d < 5) ? Wu0[d] : 0.f;
            prepF[HEADO + 8 + tid] = (d < 5) ? bu0[d] : 0.f;
        }
    }
}

// ---------------- sim: MFMA MLP, 32 paths/wave, compact LDS, true dW prefetch ----------------
__global__ __launch_bounds__(THB_SIM, 8) void sim_kernel(
    const float* __restrict__ x_in, const float* __restrict__ dW,
    const float* __restrict__ Wo, const float* __restrict__ bo,
    const float* __restrict__ Wk, const float* __restrict__ bk,
    float* __restrict__ ws, int* __restrict__ ctrl, float* __restrict__ out,
    const float* __restrict__ prepF)
{
    __shared__ int4 LsI4[PREP_I4];     // 35.9 KiB -> 4 blocks/CU (32 waves)
    __shared__ float red[8][5];
    __shared__ int lastF;
    const int tid = threadIdx.x;
    const int l = tid & 63;
    const int g = l >> 5;
    const bool gm = (g == 0);
    const int row = l & 31;
    const int p = blockIdx.x * 256 + (tid >> 6) * 32 + row;

    {   // stage compact prep into LDS
        const int4* gp4 = (const int4*)prepF;
        for (int i = tid; i < PREP_I4; i += THB_SIM) LsI4[i] = gp4[i];
    }
    const int* LsB = (const int*)LsI4;

    float x = x_in[p];

    // softmax head
    float z[11], zm = -1e30f;
#pragma unroll
    for (int j = 0; j < 11; j++) {
        z[j] = fmaf(x, Wo[j], bo[j]);
        zm = fmaxf(zm, z[j]);
    }
    float se = 0.f;
#pragma unroll
    for (int j = 0; j < 11; j++) se += __expf(z[j] - zm);
    float smv = __expf(z[10] - zm) / se;

    float K0 = 1.f + 0.25f * tanhf(fmaf(x, Wk[0], bk[0]));

    // alpha in layer-3 C-layout: reg r -> asset r+4g (g1 r>0 -> exact 0)
    float a[4];
    {
        float4 w4 = *(const float4*)(prepF + HEADO + g * 4);
        float4 b4 = *(const float4*)(prepF + HEADO + 8 + g * 4);
        a[0] = fmaf(x, w4.x, b4.x); a[1] = fmaf(x, w4.y, b4.y);
        a[2] = fmaf(x, w4.z, b4.z); a[3] = fmaf(x, w4.w, b4.w);
    }
    float S[4] = {1.f, 1.f, 1.f, 1.f}, Nm1[4];
    float SQ0 = 1.f, dNs = 0.f;
#pragma unroll
    for (int e = 0; e < 4; e++) Nm1[e] = a[e];

    // raw dW registers for current step (select deferred to consume point)
    float c0, c1, c2, c3, c4;
    {
        const float* pw = dW + (size_t)p * 5;
        c0 = pw[0]; c1 = pw[1]; c2 = pw[2]; c3 = pw[3]; c4 = pw[4];
    }

    __syncthreads();   // LDS staging complete

    f32x16 zv;
#pragma unroll
    for (int i = 0; i < 16; i++) zv[i] = 0.f;

#pragma unroll 1
    for (int n = 1; n <= NST; n++) {
        // issue next step's raw loads FIRST (consumed next iteration -> full-body slack)
        float p0 = 0.f, p1 = 0.f, p2 = 0.f, p3 = 0.f, p4 = 0.f;
        if (n < NST) {
            const float* pw = dW + ((size_t)n * BB + p) * 5;
            p0 = pw[0]; p1 = pw[1]; p2 = pw[2]; p3 = pw[3]; p4 = pw[4];
        }
        // select current step's noise at CONSUME point (waitcnt for c* lands here, counted)
        float dwc[4];
        dwc[0] = gm ? c0 : c4;
        dwc[1] = gm ? c1 : 0.f; dwc[2] = gm ? c2 : 0.f; dwc[3] = gm ? c3 : 0.f;

        // Euler step (per-lane 4 asset slots; g1 extra slots are exact zeros)
        float du = 0.f, us = 0.f;
#pragma unroll
        for (int e = 0; e < 4; e++) {
            float f = fmaf(SIGc, dwc[e], BHc);
            du = fmaf(a[e], f, du);
            us += a[e];
            float Np = a[e] * __builtin_amdgcn_rcpf(S[e]);
            dNs += fabsf(Np - Nm1[e]);
            Nm1[e] = Np;
            S[e] = fmaf(S[e], f, S[e]);          // S *= 1 + BH + SIG*dw
        }
        SQ0 = fmaf(SQ0, fmaf(SIGc, dwc[0], RHc), SQ0);
        du += __shfl_xor(du, 32);
        us += __shfl_xor(us, 32);
        x = fmaf(x - us, RHc, x) + du;

        if (n < NST) {
            const int* sb = LsB + (n - 1) * CSTR;
            // fragment LDS reads (compact layout)
            int4 cA20 = ((const int4*)sb)[l];
            int a21lo = sb[256 + 2 * l], a21hi = sb[256 + 2 * l + 1];
            int4 cA30 = make_int4(0, 0, 0, 0);
            int a31lo = 0, a31hi = 0;
            if (row < 5) {
                int t = g * 5 + row;
                cA30 = ((const int4*)(sb + 384))[t];
                a31lo = sb[424 + 2 * t]; a31hi = sb[424 + 2 * t + 1];
            }
            int4 cA21 = make_int4(a21lo, a21hi, 0, 0);
            int4 cA31 = make_int4(a31lo, a31hi, 0, 0);
            const int4* lp = (const int4*)(sb + 444) + g * 3;
            int4 cL0 = lp[0], cL1 = lp[1], cL2 = lp[2];
            // ---- layer 1 from packed bf16 (w lo, b hi) ----
            float h[12];
            {
                unsigned u;
                u = (unsigned)cL0.x; h[0]  = fmaxf(fmaf(x, bflo(u), bfhi(u)), 0.f);
                u = (unsigned)cL0.y; h[1]  = fmaxf(fmaf(x, bflo(u), bfhi(u)), 0.f);
                u = (unsigned)cL0.z; h[2]  = fmaxf(fmaf(x, bflo(u), bfhi(u)), 0.f);
                u = (unsigned)cL0.w; h[3]  = fmaxf(fmaf(x, bflo(u), bfhi(u)), 0.f);
                u = (unsigned)cL1.x; h[4]  = fmaxf(fmaf(x, bflo(u), bfhi(u)), 0.f);
                u = (unsigned)cL1.y; h[5]  = fmaxf(fmaf(x, bflo(u), bfhi(u)), 0.f);
                u = (unsigned)cL1.z; h[6]  = fmaxf(fmaf(x, bflo(u), bfhi(u)), 0.f);
                u = (unsigned)cL1.w; h[7]  = fmaxf(fmaf(x, bflo(u), bfhi(u)), 0.f);
                u = (unsigned)cL2.x; h[8]  = fmaxf(fmaf(x, bflo(u), bfhi(u)), 0.f);
                u = (unsigned)cL2.y; h[9]  = fmaxf(fmaf(x, bflo(u), bfhi(u)), 0.f);
                u = (unsigned)cL2.z; h[10] = fmaxf(fmaf(x, bflo(u), bfhi(u)), 0.f);
                u = (unsigned)cL2.w; h[11] = fmaxf(fmaf(x, bflo(u), bfhi(u)), 0.f);
            }
            BFR b1c0, b1c1;
            b1c0.u[0] = pkbf(h[0], h[1]);  b1c0.u[1] = pkbf(h[2], h[3]);
            b1c0.u[2] = pkbf(h[4], h[5]);  b1c0.u[3] = pkbf(h[6], h[7]);
            b1c1.u[0] = gm ? pkbf(h[8], h[9])   : 0x00003F80u;  // g1 k-slot20 = 1.0 (bias)
            b1c1.u[1] = gm ? pkbf(h[10], h[11]) : 0u;
            b1c1.u[2] = 0u; b1c1.u[3] = 0u;
            // ---- layer 2: D2 = W2^T * h1 (+ b2 via k-slot 20) ----
            F8 fa;
            fa.i = cA20;
            f32x16 d2 = __builtin_amdgcn_mfma_f32_32x32x16_bf16(fa.b, b1c0.b, zv, 0, 0, 0);
            fa.i = cA21;
            d2 = __builtin_amdgcn_mfma_f32_32x32x16_bf16(fa.b, b1c1.b, d2, 0, 0, 0);
            float h2r[12];
#pragma unroll
            for (int i = 0; i < 12; i++) h2r[i] = fmaxf(d2[i], 0.f);
            // ---- repack h2 C-layout -> layer-3 B-fragments (no cross-lane) ----
            BFR b2c0, b2c1;
            b2c0.u[0] = pkbf(h2r[0], h2r[1]); b2c0.u[1] = pkbf(h2r[2], h2r[3]);
            b2c0.u[2] = pkbf(h2r[4], h2r[5]); b2c0.u[3] = pkbf(h2r[6], h2r[7]);
            b2c1.u[0] = gm ? pkbf(h2r[8], h2r[9])   : 0x00003F80u;
            b2c1.u[1] = gm ? pkbf(h2r[10], h2r[11]) : 0u;
            b2c1.u[2] = 0u; b2c1.u[3] = 0u;
            // ---- layer 3: D3 = W3^T * h2 (+ b3 via k-slot 20) ----
            fa.i = cA30;
            f32x16 d3 = __builtin_amdgcn_mfma_f32_32x32x16_bf16(fa.b, b2c0.b, zv, 0, 0, 0);
            fa.i = cA31;
            d3 = __builtin_amdgcn_mfma_f32_32x32x16_bf16(fa.b, b2c1.b, d3, 0, 0, 0);
            a[0] = d3[0]; a[1] = d3[1]; a[2] = d3[2]; a[3] = d3[3];
        }
        c0 = p0; c1 = p1; c2 = p2; c3 = p3; c4 = p4;   // rotate raw dW regs
    }

    // epilogue
    float dnO = __shfl_xor(dNs, 32);
    float xx = fmaf(-CURTc, dNs + dnO, x);
    if (gm) ws[p] = xx;
    float v0 = gm ? xx : 0.f;
    float v1 = gm ? xx * xx : 0.f;
    float v2 = gm ? fmaxf(S[0] - K0, 0.f) : 0.f;
    float v3 = gm ? fmaxf(SQ0 - K0, 0.f) : 0.f;
    float v4 = gm ? smv : 0.f;

    v0 = wred(v0); v1 = wred(v1); v2 = wred(v2); v3 = wred(v3); v4 = wred(v4);
    int wid = tid >> 6, lane = tid & 63;
    if (lane == 0) { red[wid][0] = v0; red[wid][1] = v1; red[wid][2] = v2; red[wid][3] = v3; red[wid][4] = v4; }
    __syncthreads();
    if (tid == 0) {
        float s0 = 0, s1 = 0, s2 = 0, s3 = 0, s4 = 0;
#pragma unroll
        for (int w = 0; w < 8; w++) { s0 += red[w][0]; s1 += red[w][1]; s2 += red[w][2]; s3 += red[w][3]; s4 += red[w][4]; }
        float* part = ws + SIMP_OFF + blockIdx.x * 5;
        part[0] = s0; part[1] = s1; part[2] = s2; part[3] = s3; part[4] = s4;
    }
    __threadfence();
    if (tid == 0) lastF = (atomicAdd(&ctrl[CNT_OFF], 1) == NBLK_SIM - 1);
    __syncthreads();
    if (!lastF) return;
    __threadfence();

    const float* part = ws + SIMP_OFF;
    float a0 = 0, a1 = 0, a2 = 0, a3 = 0, a4 = 0;
    for (int r = tid; r < NBLK_SIM; r += THB_SIM) {
        const float* pr = part + r * 5;
        a0 += pr[0]; a1 += pr[1]; a2 += pr[2]; a3 += pr[3]; a4 += pr[4];
    }
    a0 = wred(a0); a1 = wred(a1); a2 = wred(a2); a3 = wred(a3); a4 = wred(a4);
    if (lane == 0) { red[wid][0] = a0; red[wid][1] = a1; red[wid][2] = a2; red[wid][3] = a3; red[wid][4] = a4; }
    __syncthreads();
    if (tid == 0) {
        float Sx = 0, Sx2 = 0, SP = 0, SQs = 0, Ssm = 0;
#pragma unroll
        for (int w = 0; w < 8; w++) { Sx += red[w][0]; Sx2 += red[w][1]; SP += red[w][2]; SQs += red[w][3]; Ssm += red[w][4]; }
        float invB = 1.f / (float)BB;
        float meanx = Sx * invB;
        out[0] = -meanx;
        out[1] = Sx2 * invB - meanx * meanx;
        out[4] = (SP * invB) / (DISCf * (SQs * invB) + 1e-8f);
        out[5] = 1.f + 0.25f * tanhf(fmaf(x_in[0], Wk[1], bk[1]));
        out[6] = Ssm * invB;
    }
}

// ---------------- select helpers ----------------
__device__ __forceinline__ void aggAdd(int* h, int code) {
    bool act = (code >= 0);
    unsigned long long mask = __ballot(act);
    while (mask) {
        int leader = __ffsll((unsigned long long)mask) - 1;
        int lc = __shfl(code, leader);
        unsigned long long mm = __ballot(act && code == lc);
        if ((threadIdx.x & 63) == leader) atomicAdd(&h[lc], (int)__popcll(mm));
        mask &= ~mm;
    }
}

__device__ int excl_scan1024(int v, int tid, int* wsum) {
    __syncthreads();
    int lane = tid & 63, wid = tid >> 6;
    int inc = v;
#pragma unroll
    for (int o = 1; o < 64; o <<= 1) { int u = __shfl_up(inc, o); if (lane >= o) inc += u; }
    if (lane == 63) wsum[wid] = inc;
    __syncthreads();
    if (tid < 16) {
        int wv = wsum[tid], winc = wv;
#pragma unroll
        for (int o = 1; o < 16; o <<= 1) { int u = __shfl_up(winc, o); if (tid >= o) winc += u; }
        wsum[tid] = winc - wv;
    }
    __syncthreads();
    return wsum[wid] + inc - v;
}

__global__ __launch_bounds__(H1_THR) void hist1_kernel(const float* __restrict__ xf,
                                                       int* __restrict__ ctrl)
{
    __shared__ int lh[2048];
    const int tid = threadIdx.x, bl = blockIdx.x;
    for (int i = tid; i < 2048; i += H1_THR) lh[i] = 0;
    __syncthreads();
    const float4* xf4 = (const float4*)xf;
#pragma unroll
    for (int w = 0; w < 4; w++) {
        float4 v = xf4[(size_t)bl * 4096 + w * 1024 + tid];
        aggAdd(lh, (int)(fkey(v.x) >> 21));
        aggAdd(lh, (int)(fkey(v.y) >> 21));
        aggAdd(lh, (int)(fkey(v.z) >> 21));
        aggAdd(lh, (int)(fkey(v.w) >> 21));
    }
    __syncthreads();
    int* row = ctrl + H1R_OFF + bl * 2048;
    for (int i = tid; i < 2048; i += H1_THR) row[i] = lh[i];
}

__global__ __launch_bounds__(1024) void scan1_kernel(int* __restrict__ ctrl)
{
    __shared__ int wsum[16];
    __shared__ int binT[4], remT[4];
    const int tid = threadIdx.x;
    const int* rows = ctrl + H1R_OFF;
    int c0 = 0, c1 = 0;
    for (int r = 0; r < H1_BLK; r++) {
        c0 += rows[r * 2048 + 2 * tid];
        c1 += rows[r * 2048 + 2 * tid + 1];
    }
    int s = c0 + c1;
    int E = excl_scan1024(s, tid, wsum);
    const int RK[4] = {13107, 13108, 249035, 249036};
#pragma unroll
    for (int t = 0; t < 4; t++) {
        int r = RK[t];
        if (r >= E && r < E + s) {
            if (r < E + c0) { binT[t] = 2 * tid;     remT[t] = r - E; }
            else            { binT[t] = 2 * tid + 1; remT[t] = r - E - c0; }
        }
    }
    __syncthreads();
    if (tid == 0) {
        for (int t = 0; t < 4; t++) { ctrl[ST_OFF + t] = binT[t]; ctrl[ST_OFF + 4 + t] = remT[t]; }
        for (int t = 0; t < 4; t++) {
            int g = t;
            for (int q = 0; q < t; q++) if (binT[q] == binT[t]) { g = q; break; }
            ctrl[ST_OFF + 8 + t] = g;
        }
    }
}

__global__ __launch_bounds__(W_THR) void hist2_kernel(const float* __restrict__ xf,
                                                      int* __restrict__ ctrl)
{
    const int tid = threadIdx.x, bl = blockIdx.x;
    int pf[4], gp[4];
#pragma unroll
    for (int t = 0; t < 4; t++) { pf[t] = ctrl[ST_OFF + t]; gp[t] = ctrl[ST_OFF + 8 + t]; }
    float4 v = ((const float4*)xf)[(size_t)bl * W_THR + tid];
    float xv[4] = {v.x, v.y, v.z, v.w};
#pragma unroll
    for (int k = 0; k < 4; k++) {
        unsigned u = fkey(xv[k]);
        unsigned hi = u >> 21;
        int bin = (int)((u >> 10) & 2047u);
        int code = -1;
#pragma unroll
        for (int t = 0; t < 4; t++)
            if (gp[t] == t && (unsigned)pf[t] == hi) code = t * 2048 + bin;
        aggAdd(ctrl + H2_OFF, code);
    }
}

__global__ __launch_bounds__(1024) void scan2_kernel(int* __restrict__ ctrl)
{
    __shared__ int wsum[16];
    __shared__ int binT[4], remT[4];
    const int tid = threadIdx.x;
    for (int t = 0; t < 4; t++) {
        int g = ctrl[ST_OFF + 8 + t], rank = ctrl[ST_OFF + 4 + t];
        const int* h = ctrl + H2_OFF + g * 2048;
        int c0 = h[2 * tid], c1 = h[2 * tid + 1];
        int s = c0 + c1;
        int E = excl_scan1024(s, tid, wsum);
        if (rank >= E && rank < E + s) {
            if (rank < E + c0) { binT[t] = 2 * tid;     remT[t] = rank - E; }
            else               { binT[t] = 2 * tid + 1; remT[t] = rank - E - c0; }
        }
        __syncthreads();
    }
    if (tid == 0) {
        int P2n[4];
        for (int t = 0; t < 4; t++) {
            P2n[t] = (ctrl[ST_OFF + t] << 11) | binT[t];
            ctrl[ST_OFF + 12 + t] = P2n[t];
            ctrl[ST_OFF + 16 + t] = remT[t];
        }
        for (int t = 0; t < 4; t++) {
            int g = t;
            for (int q = 0; q < t; q++) if (P2n[q] == P2n[t]) { g = q; break; }
            ctrl[ST_OFF + 20 + t] = g;
        }
    }
}

__global__ __launch_bounds__(W_THR) void hist3_kernel(const float* __restrict__ xf,
                                                      int* __restrict__ ctrl)
{
    const int tid = threadIdx.x, bl = blockIdx.x;
    int pf[4], gp[4];
#pragma unroll
    for (int t = 0; t < 4; t++) { pf[t] = ctrl[ST_OFF + 12 + t]; gp[t] = ctrl[ST_OFF + 20 + t]; }
    float4 v = ((const float4*)xf)[(size_t)bl * W_THR + tid];
    float xv[4] = {v.x, v.y, v.z, v.w};
#pragma unroll
    for (int k = 0; k < 4; k++) {
        unsigned u = fkey(xv[k]);
        unsigned hi = u >> 10;
        int bin = (int)(u & 1023u);
        int code = -1;
#pragma unroll
        for (int t = 0; t < 4; t++)
            if (gp[t] == t && (unsigned)pf[t] == hi) code = t * 1024 + bin;
        aggAdd(ctrl + H3_OFF, code);
    }
}

__global__ __launch_bounds__(1024) void scan3_kernel(int* __restrict__ ctrl)
{
    __shared__ int wsum[16];
    __shared__ int binT[4];
    const int tid = threadIdx.x;
    for (int t = 0; t < 4; t++) {
        int g = ctrl[ST_OFF + 20 + t], rank = ctrl[ST_OFF + 16 + t];
        const int* h = ctrl + H3_OFF + g * 1024;
        int s = h[tid];
        int E = excl_scan1024(s, tid, wsum);
        if (rank >= E && rank < E + s) binT[t] = tid;
        __syncthreads();
    }
    if (tid == 0) {
        float* sf = (float*)(ctrl + SF_OFF);
        float v[4];
        for (int t = 0; t < 4; t++) {
            unsigned key = ((unsigned)ctrl[ST_OFF + 12 + t] << 10) | (unsigned)binT[t];
            v[t] = funkey(key);
            sf[t] = v[t];
        }
        sf[4] = v[0] + 0.15f * (v[1] - v[0]);  // p5  (idx 0.05*(B-1)=13107.15)
        sf[5] = v[2] + 0.85f * (v[3] - v[2]);  // p95 (idx 0.95*(B-1)=249035.85)
    }
}

__global__ __launch_bounds__(W_THR) void tail_kernel(const float* __restrict__ xf,
                                                     const int* __restrict__ ctrl,
                                                     float* __restrict__ ws)
{
    __shared__ float frd[4][4];
    const int tid = threadIdx.x, bl = blockIdx.x;
    const float* sf = (const float*)(ctrl + SF_OFF);
    const float p5 = sf[4], p95 = sf[5];
    float4 v = ((const float4*)xf)[(size_t)bl * W_THR + tid];
    float xv[4] = {v.x, v.y, v.z, v.w};
    float slo = 0.f, clo = 0.f, shi = 0.f, chi = 0.f;
#pragma unroll
    for (int k = 0; k < 4; k++) {
        float x = xv[k];
        if (x < p5)  { slo += x; clo += 1.f; }
        if (x > p95) { shi += x; chi += 1.f; }
    }
    slo = wred(slo); clo = wred(clo); shi = wred(shi); chi = wred(chi);
    int wid = tid >> 6, lane = tid & 63;
    if (lane == 0) { frd[wid][0] = slo; frd[wid][1] = clo; frd[wid][2] = shi; frd[wid][3] = chi; }
    __syncthreads();
    if (tid == 0) {
        float s0 = 0, s1 = 0, s2 = 0, s3 = 0;
#pragma unroll
        for (int w = 0; w < 4; w++) { s0 += frd[w][0]; s1 += frd[w][1]; s2 += frd[w][2]; s3 += frd[w][3]; }
        float* tp = ws + TAILP_OFF + bl * 4;
        tp[0] = s0; tp[1] = s1; tp[2] = s2; tp[3] = s3;
    }
}

__global__ __launch_bounds__(256) void tailfin_kernel(const float* __restrict__ ws,
                                                      float* __restrict__ out)
{
    __shared__ float frd[4][4];
    const int tid = threadIdx.x;
    const float* tp = ws + TAILP_OFF;
    float a0 = tp[tid * 4 + 0], a1 = tp[tid * 4 + 1], a2 = tp[tid * 4 + 2], a3 = tp[tid * 4 + 3];
    a0 = wred(a0); a1 = wred(a1); a2 = wred(a2); a3 = wred(a3);
    int wid = tid >> 6, lane = tid & 63;
    if (lane == 0) { frd[wid][0] = a0; frd[wid][1] = a1; frd[wid][2] = a2; frd[wid][3] = a3; }
    __syncthreads();
    if (tid == 0) {
        float Slo = 0, Clo = 0, Shi = 0, Chi = 0;
#pragma unroll
        for (int w = 0; w < 4; w++) { Slo += frd[w][0]; Clo += frd[w][1]; Shi += frd[w][2]; Chi += frd[w][3]; }
        out[2] = -Slo / fmaxf(Clo, 1.f);
        out[3] = -Shi / fmaxf(Chi, 1.f);
    }
}

// ---------------- host ----------------
extern "C" void kernel_launch(void* const* d_in, const int* in_sizes, int n_in,
                              void* d_out, int out_size, void* d_ws, size_t ws_size,
                              hipStream_t stream)
{
    const float* x_in = (const float*)d_in[0];
    const float* dW   = (const float*)d_in[1];
    const float* Wo   = (const float*)d_in[2];
    const float* bo   = (const float*)d_in[3];
    const float* Wk   = (const float*)d_in[4];
    const float* bk   = (const float*)d_in[5];
    const float* Wu0  = (const float*)d_in[6];
    const float* bu0  = (const float*)d_in[7];
    const float* W1   = (const float*)d_in[8];
    const float* b1   = (const float*)d_in[9];
    const float* W2   = (const float*)d_in[10];
    const float* b2   = (const float*)d_in[11];
    const float* W3   = (const float*)d_in[12];
    const float* b3   = (const float*)d_in[13];
    float* ws   = (float*)d_ws;
    int* ctrl   = (int*)d_ws + ICTRL;
    float* prep = ws + PREP_OFF;
    float* out  = (float*)d_out;

    zero_kernel<<<(ZTOT + 1023) / 1024, 1024, 0, stream>>>(ctrl);
    prep_kernel<<<20, 256, 0, stream>>>(Wu0, bu0, W1, b1, W2, b2, W3, b3, prep);
    sim_kernel<<<NBLK_SIM, THB_SIM, 0, stream>>>(x_in, dW, Wo, bo, Wk, bk, ws, ctrl, out, prep);
    hist1_kernel<<<H1_BLK, H1_THR, 0, stream>>>(ws, ctrl);
    scan1_kernel<<<1, 1024, 0, stream>>>(ctrl);
    hist2_kernel<<<W_BLK, W_THR, 0, stream>>>(ws, ctrl);
    scan2_kernel<<<1, 1024, 0, stream>>>(ctrl);
    hist3_kernel<<<W_BLK, W_THR, 0, stream>>>(ws, ctrl);
    scan3_kernel<<<1, 1024, 0, stream>>>(ctrl);
    tail_kernel<<<W_BLK, W_THR, 0, stream>>>(ws, ctrl, ws);
    tailfin_kernel<<<1, 256, 0, stream>>>(ws, out);
}

// Round 11
// 275.275 us; speedup vs baseline: 1.0379x; 1.0379x over previous
//
#include <hip/hip_runtime.h>
#include <hip/hip_bf16.h>
#include <math.h>

// ---------------- problem constants ----------------
#define BB 262144
#define NST 20
#define RHc 0.006f            // R*H
#define BHc 0.01f             // B_DRIFT*H
#define SIGc 0.2f
#define CURTc 0.005f
#define DISCf 0.8869204367171575f   // exp(-0.12)

// ---------------- launch geometry ----------------
#define THB_SIM 512
#define NBLK_SIM 1024          // 256 paths per block (8 waves x 32)
#define H1_BLK 16
#define H1_THR 1024
#define W_BLK 256
#define W_THR 256

// ---------------- workspace layout (floats from ws base unless noted) ----------------
#define SIMP_OFF  BB                          // float[NBLK_SIM*5]
#define TAILP_OFF (SIMP_OFF + NBLK_SIM * 5)   // float[W_BLK*4]
#define ICTRL     (TAILP_OFF + W_BLK * 4)     // int region base
// ctrl ints:
#define H2_OFF 0                      // 4*2048
#define H3_OFF 8192                   // 4*1024
#define CNT_OFF 12288
#define ST_OFF  12296
#define SF_OFF  12320
#define ZTOT    12289
#define H1R_OFF 12352                 // 16 rows x 2048 ints (written AFTER sim)
// prep region OVERLAYS H1R (prep consumed by sim; H1R written by hist1 post-sim)
#define PREP_OFF (ICTRL + H1R_OFF)
// compact per-step layout (dwords): A2c0 256 | A2c1 128 | A3c0 40 | A3c1 20 | L1p 24 | pad 4
#define CSTR 472
#define HEADO (19 * CSTR)             // Wu0m[8], bu0m[8]
#define PREP_DW (HEADO + 16)          // 8984 dwords = 35.9 KB (fits H1R overlay 32768 ints)
#define PREP_I4 2246                  // ceil(PREP_DW/4)

// ---------------- types / helpers ----------------
typedef float f32x16 __attribute__((ext_vector_type(16)));
typedef short bf16x8 __attribute__((ext_vector_type(8)));
union F8  { int4 i; bf16x8 b; };
union BFR { unsigned u[4]; int4 i; bf16x8 b; };

__device__ __forceinline__ unsigned pkbf(float lo, float hi) {   // 1 VALU op
    unsigned r;
    asm("v_cvt_pk_bf16_f32 %0, %1, %2" : "=v"(r) : "v"(lo), "v"(hi));
    return r;
}
__device__ __forceinline__ float bflo(unsigned u) { return __uint_as_float(u << 16); }
__device__ __forceinline__ float bfhi(unsigned u) { return __uint_as_float(u & 0xffff0000u); }
__device__ __forceinline__ unsigned fkey(float f) {
    unsigned u = __float_as_uint(f);
    return (u & 0x80000000u) ? ~u : (u | 0x80000000u);
}
__device__ __forceinline__ float funkey(unsigned k) {
    return __uint_as_float((k & 0x80000000u) ? (k ^ 0x80000000u) : ~k);
}
__device__ __forceinline__ float wred(float v) {
#pragma unroll
    for (int o = 32; o > 0; o >>= 1) v += __shfl_down(v, o);
    return v;
}
__device__ __forceinline__ unsigned short f2bf(float f) {   // RNE
    unsigned u = __float_as_uint(f);
    unsigned r = u + 0x7fffu + ((u >> 16) & 1u);
    return (unsigned short)(r >> 16);
}
__device__ __forceinline__ int pk2(float lo, float hi) {
    return (int)(((unsigned)f2bf(hi) << 16) | f2bf(lo));
}

__global__ void zero_kernel(int* __restrict__ ctrl) {
    int i = blockIdx.x * blockDim.x + threadIdx.x;
    if (i < ZTOT) ctrl[i] = 0;
}

// ---------------- prep: compact MFMA fragment form ----------------
// k-slot labeling (32x32x16 bf16): lane l, dword v, half h:
//   k = 16c + 8*(v>>1) + 4*(l>>5) + 2*(v&1) + h ; A row / B col = l&31
// Bias fold: A k-slot 20 holds b2/b3; B k-slot 20 holds 1.0 for g1 lanes.
__global__ void prep_kernel(const float* __restrict__ Wu0, const float* __restrict__ bu0,
                            const float* __restrict__ W1, const float* __restrict__ b1,
                            const float* __restrict__ W2, const float* __restrict__ b2,
                            const float* __restrict__ W3, const float* __restrict__ b3,
                            float* __restrict__ prepF)
{
    const int s = blockIdx.x, tid = threadIdx.x;
    int* prepI = (int*)prepF;
    if (s < 19) {
        // A2c0: 256 dwords (lane l, v) — c=0, kb = 8*(v>>1)+4g+2*(v&1) (<=14)
        {
            int t = tid;  // 256 threads
            int l = t >> 2, v = t & 3, g = l >> 5, row = l & 31;
            int kb = 8 * (v >> 1) + 4 * g + 2 * (v & 1);
            float lo = (row < 20) ? W2[s * 400 + kb * 20 + row] : 0.f;
            float hi = (row < 20) ? W2[s * 400 + (kb + 1) * 20 + row] : 0.f;
            prepI[s * CSTR + t] = pk2(lo, hi);
        }
        // A2c1 compact: 128 dwords (lane l, vv) — kb = 16+4g+2vv
        if (tid < 128) {
            int l = tid >> 1, vv = tid & 1, g = l >> 5, row = l & 31;
            int kb = 16 + 4 * g + 2 * vv;
            float lo = 0.f, hi = 0.f;
            if (row < 20) {
                if (kb < 20)       lo = W2[s * 400 + kb * 20 + row];
                else if (kb == 20) lo = b2[s * 20 + row];
                if (kb + 1 < 20)   hi = W2[s * 400 + (kb + 1) * 20 + row];
            }
            prepI[s * CSTR + 256 + tid] = pk2(lo, hi);
        }
        // A3c0 compact: 40 dwords (e = g*5+row in 0..9, v)
        if (tid < 40) {
            int e = tid >> 2, v = tid & 3, g = e / 5, row = e % 5;
            int kb = 8 * (v >> 1) + 4 * g + 2 * (v & 1);
            float lo = W3[s * 100 + kb * 5 + row];
            float hi = W3[s * 100 + (kb + 1) * 5 + row];
            prepI[s * CSTR + 384 + tid] = pk2(lo, hi);
        }
        // A3c1 compact: 20 dwords (e, vv) — kb = 16+4g+2vv
        if (tid < 20) {
            int e = tid >> 1, vv = tid & 1, g = e / 5, row = e % 5;
            int kb = 16 + 4 * g + 2 * vv;
            float lo = 0.f, hi = 0.f;
            if (kb < 20)       lo = W3[s * 100 + kb * 5 + row];
            else if (kb == 20) lo = b3[s * 5 + row];
            if (kb + 1 < 20)   hi = W3[s * 100 + (kb + 1) * 5 + row];
            prepI[s * CSTR + 424 + tid] = pk2(lo, hi);
        }
        // L1p: 24 dwords (w lo, b hi), neuron order per B k-slot map
        if (tid < 24) {
            int g = tid / 12, j = tid % 12;
            int n = (j < 4) ? 4 * g + j : (j < 8) ? 8 + 4 * g + (j - 4) : 16 + 4 * g + (j - 8);
            unsigned w = 0, b = 0;
            if (n < 20) { w = f2bf(W1[s * 20 + n]); b = f2bf(b1[s * 20 + n]); }
            prepI[s * CSTR + 444 + tid] = (int)((b << 16) | w);
        }
        if (tid >= 24 && tid < 28) prepI[s * CSTR + 444 + tid] = 0;  // pad 468..471
    } else {
        if (tid < 8) {    // Wu0/bu0 mapped to alpha C-regs 0-3 per g (d = r + 4g)
            int g = tid >> 2, r = tid & 3, d = r + 4 * g;
            prepF[HEADO + tid]     = (d < 5) ? Wu0[d] : 0.f;
            prepF[HEADO + 8 + tid] = (d < 5) ? bu0[d] : 0.f;
        }
    }
}

// ---------------- sim: MFMA MLP, 32 paths/wave, compact LDS, true dW prefetch ----------------
// min-waves=6 -> VGPR cap 85: guaranteed no spill (R9 codegen used 52), LDS gives 4 blocks/CU.
__global__ __launch_bounds__(THB_SIM, 6) void sim_kernel(
    const float* __restrict__ x_in, const float* __restrict__ dW,
    const float* __restrict__ Wo, const float* __restrict__ bo,
    const float* __restrict__ Wk, const float* __restrict__ bk,
    float* __restrict__ ws, int* __restrict__ ctrl, float* __restrict__ out,
    const float* __restrict__ prepF)
{
    __shared__ int4 LsI4[PREP_I4];     // 35.9 KiB -> 4 blocks/CU (32 waves)
    __shared__ float red[8][5];
    __shared__ int lastF;
    const int tid = threadIdx.x;
    const int l = tid & 63;
    const int g = l >> 5;
    const bool gm = (g == 0);
    const int row = l & 31;
    const int p = blockIdx.x * 256 + (tid >> 6) * 32 + row;

    {   // stage compact prep into LDS
        const int4* gp4 = (const int4*)prepF;
        for (int i = tid; i < PREP_I4; i += THB_SIM) LsI4[i] = gp4[i];
    }
    const int* LsB = (const int*)LsI4;

    float x = x_in[p];

    // softmax head
    float z[11], zm = -1e30f;
#pragma unroll
    for (int j = 0; j < 11; j++) {
        z[j] = fmaf(x, Wo[j], bo[j]);
        zm = fmaxf(zm, z[j]);
    }
    float se = 0.f;
#pragma unroll
    for (int j = 0; j < 11; j++) se += __expf(z[j] - zm);
    float smv = __expf(z[10] - zm) / se;

    float K0 = 1.f + 0.25f * tanhf(fmaf(x, Wk[0], bk[0]));

    // alpha in layer-3 C-layout: reg r -> asset r+4g (g1 r>0 -> exact 0)
    float a[4];
    {
        float4 w4 = *(const float4*)(prepF + HEADO + g * 4);
        float4 b4 = *(const float4*)(prepF + HEADO + 8 + g * 4);
        a[0] = fmaf(x, w4.x, b4.x); a[1] = fmaf(x, w4.y, b4.y);
        a[2] = fmaf(x, w4.z, b4.z); a[3] = fmaf(x, w4.w, b4.w);
    }
    float S[4] = {1.f, 1.f, 1.f, 1.f}, Nm1[4];
    float SQ0 = 1.f, dNs = 0.f;
#pragma unroll
    for (int e = 0; e < 4; e++) Nm1[e] = a[e];

    // raw dW registers for current step (select deferred to consume point)
    float c0, c1, c2, c3, c4;
    {
        const float* pw = dW + (size_t)p * 5;
        c0 = pw[0]; c1 = pw[1]; c2 = pw[2]; c3 = pw[3]; c4 = pw[4];
    }

    __syncthreads();   // LDS staging complete

    f32x16 zv;
#pragma unroll
    for (int i = 0; i < 16; i++) zv[i] = 0.f;

#pragma unroll 1
    for (int n = 1; n <= NST; n++) {
        // issue next step's raw loads FIRST (consumed next iteration -> full-body slack)
        float p0 = 0.f, p1 = 0.f, p2 = 0.f, p3 = 0.f, p4 = 0.f;
        if (n < NST) {
            const float* pw = dW + ((size_t)n * BB + p) * 5;
            p0 = pw[0]; p1 = pw[1]; p2 = pw[2]; p3 = pw[3]; p4 = pw[4];
        }
        // select current step's noise at CONSUME point
        float dwc[4];
        dwc[0] = gm ? c0 : c4;
        dwc[1] = gm ? c1 : 0.f; dwc[2] = gm ? c2 : 0.f; dwc[3] = gm ? c3 : 0.f;

        // Euler step (per-lane 4 asset slots; g1 extra slots are exact zeros)
        float du = 0.f, us = 0.f;
#pragma unroll
        for (int e = 0; e < 4; e++) {
            float f = fmaf(SIGc, dwc[e], BHc);
            du = fmaf(a[e], f, du);
            us += a[e];
            float Np = a[e] * __builtin_amdgcn_rcpf(S[e]);
            dNs += fabsf(Np - Nm1[e]);
            Nm1[e] = Np;
            S[e] = fmaf(S[e], f, S[e]);          // S *= 1 + BH + SIG*dw
        }
        SQ0 = fmaf(SQ0, fmaf(SIGc, dwc[0], RHc), SQ0);
        du += __shfl_xor(du, 32);
        us += __shfl_xor(us, 32);
        x = fmaf(x - us, RHc, x) + du;

        if (n < NST) {
            const int* sb = LsB + (n - 1) * CSTR;
            // fragment LDS reads (compact layout)
            int4 cA20 = ((const int4*)sb)[l];
            int a21lo = sb[256 + 2 * l], a21hi = sb[256 + 2 * l + 1];
            int4 cA30 = make_int4(0, 0, 0, 0);
            int a31lo = 0, a31hi = 0;
            if (row < 5) {
                int t = g * 5 + row;
                cA30 = ((const int4*)(sb + 384))[t];
                a31lo = sb[424 + 2 * t]; a31hi = sb[424 + 2 * t + 1];
            }
            int4 cA21 = make_int4(a21lo, a21hi, 0, 0);
            int4 cA31 = make_int4(a31lo, a31hi, 0, 0);
            const int4* lp = (const int4*)(sb + 444) + g * 3;
            int4 cL0 = lp[0], cL1 = lp[1], cL2 = lp[2];
            // ---- layer 1 from packed bf16 (w lo, b hi) ----
            float h[12];
            {
                unsigned u;
                u = (unsigned)cL0.x; h[0]  = fmaxf(fmaf(x, bflo(u), bfhi(u)), 0.f);
                u = (unsigned)cL0.y; h[1]  = fmaxf(fmaf(x, bflo(u), bfhi(u)), 0.f);
                u = (unsigned)cL0.z; h[2]  = fmaxf(fmaf(x, bflo(u), bfhi(u)), 0.f);
                u = (unsigned)cL0.w; h[3]  = fmaxf(fmaf(x, bflo(u), bfhi(u)), 0.f);
                u = (unsigned)cL1.x; h[4]  = fmaxf(fmaf(x, bflo(u), bfhi(u)), 0.f);
                u = (unsigned)cL1.y; h[5]  = fmaxf(fmaf(x, bflo(u), bfhi(u)), 0.f);
                u = (unsigned)cL1.z; h[6]  = fmaxf(fmaf(x, bflo(u), bfhi(u)), 0.f);
                u = (unsigned)cL1.w; h[7]  = fmaxf(fmaf(x, bflo(u), bfhi(u)), 0.f);
                u = (unsigned)cL2.x; h[8]  = fmaxf(fmaf(x, bflo(u), bfhi(u)), 0.f);
                u = (unsigned)cL2.y; h[9]  = fmaxf(fmaf(x, bflo(u), bfhi(u)), 0.f);
                u = (unsigned)cL2.z; h[10] = fmaxf(fmaf(x, bflo(u), bfhi(u)), 0.f);
                u = (unsigned)cL2.w; h[11] = fmaxf(fmaf(x, bflo(u), bfhi(u)), 0.f);
            }
            BFR b1c0, b1c1;
            b1c0.u[0] = pkbf(h[0], h[1]);  b1c0.u[1] = pkbf(h[2], h[3]);
            b1c0.u[2] = pkbf(h[4], h[5]);  b1c0.u[3] = pkbf(h[6], h[7]);
            b1c1.u[0] = gm ? pkbf(h[8], h[9])   : 0x00003F80u;  // g1 k-slot20 = 1.0 (bias)
            b1c1.u[1] = gm ? pkbf(h[10], h[11]) : 0u;
            b1c1.u[2] = 0u; b1c1.u[3] = 0u;
            // ---- layer 2: D2 = W2^T * h1 (+ b2 via k-slot 20) ----
            F8 fa;
            fa.i = cA20;
            f32x16 d2 = __builtin_amdgcn_mfma_f32_32x32x16_bf16(fa.b, b1c0.b, zv, 0, 0, 0);
            fa.i = cA21;
            d2 = __builtin_amdgcn_mfma_f32_32x32x16_bf16(fa.b, b1c1.b, d2, 0, 0, 0);
            float h2r[12];
#pragma unroll
            for (int i = 0; i < 12; i++) h2r[i] = fmaxf(d2[i], 0.f);
            // ---- repack h2 C-layout -> layer-3 B-fragments (no cross-lane) ----
            BFR b2c0, b2c1;
            b2c0.u[0] = pkbf(h2r[0], h2r[1]); b2c0.u[1] = pkbf(h2r[2], h2r[3]);
            b2c0.u[2] = pkbf(h2r[4], h2r[5]); b2c0.u[3] = pkbf(h2r[6], h2r[7]);
            b2c1.u[0] = gm ? pkbf(h2r[8], h2r[9])   : 0x00003F80u;
            b2c1.u[1] = gm ? pkbf(h2r[10], h2r[11]) : 0u;
            b2c1.u[2] = 0u; b2c1.u[3] = 0u;
            // ---- layer 3: D3 = W3^T * h2 (+ b3 via k-slot 20) ----
            fa.i = cA30;
            f32x16 d3 = __builtin_amdgcn_mfma_f32_32x32x16_bf16(fa.b, b2c0.b, zv, 0, 0, 0);
            fa.i = cA31;
            d3 = __builtin_amdgcn_mfma_f32_32x32x16_bf16(fa.b, b2c1.b, d3, 0, 0, 0);
            a[0] = d3[0]; a[1] = d3[1]; a[2] = d3[2]; a[3] = d3[3];
        }
        c0 = p0; c1 = p1; c2 = p2; c3 = p3; c4 = p4;   // rotate raw dW regs
    }

    // epilogue
    float dnO = __shfl_xor(dNs, 32);
    float xx = fmaf(-CURTc, dNs + dnO, x);
    if (gm) ws[p] = xx;
    float v0 = gm ? xx : 0.f;
    float v1 = gm ? xx * xx : 0.f;
    float v2 = gm ? fmaxf(S[0] - K0, 0.f) : 0.f;
    float v3 = gm ? fmaxf(SQ0 - K0, 0.f) : 0.f;
    float v4 = gm ? smv : 0.f;

    v0 = wred(v0); v1 = wred(v1); v2 = wred(v2); v3 = wred(v3); v4 = wred(v4);
    int wid = tid >> 6, lane = tid & 63;
    if (lane == 0) { red[wid][0] = v0; red[wid][1] = v1; red[wid][2] = v2; red[wid][3] = v3; red[wid][4] = v4; }
    __syncthreads();
    if (tid == 0) {
        float s0 = 0, s1 = 0, s2 = 0, s3 = 0, s4 = 0;
#pragma unroll
        for (int w = 0; w < 8; w++) { s0 += red[w][0]; s1 += red[w][1]; s2 += red[w][2]; s3 += red[w][3]; s4 += red[w][4]; }
        float* part = ws + SIMP_OFF + blockIdx.x * 5;
        part[0] = s0; part[1] = s1; part[2] = s2; part[3] = s3; part[4] = s4;
    }
    __threadfence();
    if (tid == 0) lastF = (atomicAdd(&ctrl[CNT_OFF], 1) == NBLK_SIM - 1);
    __syncthreads();
    if (!lastF) return;
    __threadfence();

    const float* part = ws + SIMP_OFF;
    float a0 = 0, a1 = 0, a2 = 0, a3 = 0, a4 = 0;
    for (int r = tid; r < NBLK_SIM; r += THB_SIM) {
        const float* pr = part + r * 5;
        a0 += pr[0]; a1 += pr[1]; a2 += pr[2]; a3 += pr[3]; a4 += pr[4];
    }
    a0 = wred(a0); a1 = wred(a1); a2 = wred(a2); a3 = wred(a3); a4 = wred(a4);
    if (lane == 0) { red[wid][0] = a0; red[wid][1] = a1; red[wid][2] = a2; red[wid][3] = a3; red[wid][4] = a4; }
    __syncthreads();
    if (tid == 0) {
        float Sx = 0, Sx2 = 0, SP = 0, SQs = 0, Ssm = 0;
#pragma unroll
        for (int w = 0; w < 8; w++) { Sx += red[w][0]; Sx2 += red[w][1]; SP += red[w][2]; SQs += red[w][3]; Ssm += red[w][4]; }
        float invB = 1.f / (float)BB;
        float meanx = Sx * invB;
        out[0] = -meanx;
        out[1] = Sx2 * invB - meanx * meanx;
        out[4] = (SP * invB) / (DISCf * (SQs * invB) + 1e-8f);
        out[5] = 1.f + 0.25f * tanhf(fmaf(x_in[0], Wk[1], bk[1]));
        out[6] = Ssm * invB;
    }
}

// ---------------- select helpers ----------------
__device__ __forceinline__ void aggAdd(int* h, int code) {
    bool act = (code >= 0);
    unsigned long long mask = __ballot(act);
    while (mask) {
        int leader = __ffsll((unsigned long long)mask) - 1;
        int lc = __shfl(code, leader);
        unsigned long long mm = __ballot(act && code == lc);
        if ((threadIdx.x & 63) == leader) atomicAdd(&h[lc], (int)__popcll(mm));
        mask &= ~mm;
    }
}

__device__ int excl_scan1024(int v, int tid, int* wsum) {
    __syncthreads();
    int lane = tid & 63, wid = tid >> 6;
    int inc = v;
#pragma unroll
    for (int o = 1; o < 64; o <<= 1) { int u = __shfl_up(inc, o); if (lane >= o) inc += u; }
    if (lane == 63) wsum[wid] = inc;
    __syncthreads();
    if (tid < 16) {
        int wv = wsum[tid], winc = wv;
#pragma unroll
        for (int o = 1; o < 16; o <<= 1) { int u = __shfl_up(winc, o); if (tid >= o) winc += u; }
        wsum[tid] = winc - wv;
    }
    __syncthreads();
    return wsum[wid] + inc - v;
}

__global__ __launch_bounds__(H1_THR) void hist1_kernel(const float* __restrict__ xf,
                                                       int* __restrict__ ctrl)
{
    __shared__ int lh[2048];
    const int tid = threadIdx.x, bl = blockIdx.x;
    for (int i = tid; i < 2048; i += H1_THR) lh[i] = 0;
    __syncthreads();
    const float4* xf4 = (const float4*)xf;
#pragma unroll
    for (int w = 0; w < 4; w++) {
        float4 v = xf4[(size_t)bl * 4096 + w * 1024 + tid];
        aggAdd(lh, (int)(fkey(v.x) >> 21));
        aggAdd(lh, (int)(fkey(v.y) >> 21));
        aggAdd(lh, (int)(fkey(v.z) >> 21));
        aggAdd(lh, (int)(fkey(v.w) >> 21));
    }
    __syncthreads();
    int* row = ctrl + H1R_OFF + bl * 2048;
    for (int i = tid; i < 2048; i += H1_THR) row[i] = lh[i];
}

__global__ __launch_bounds__(1024) void scan1_kernel(int* __restrict__ ctrl)
{
    __shared__ int wsum[16];
    __shared__ int binT[4], remT[4];
    const int tid = threadIdx.x;
    const int* rows = ctrl + H1R_OFF;
    int c0 = 0, c1 = 0;
    for (int r = 0; r < H1_BLK; r++) {
        c0 += rows[r * 2048 + 2 * tid];
        c1 += rows[r * 2048 + 2 * tid + 1];
    }
    int s = c0 + c1;
    int E = excl_scan1024(s, tid, wsum);
    const int RK[4] = {13107, 13108, 249035, 249036};
#pragma unroll
    for (int t = 0; t < 4; t++) {
        int r = RK[t];
        if (r >= E && r < E + s) {
            if (r < E + c0) { binT[t] = 2 * tid;     remT[t] = r - E; }
            else            { binT[t] = 2 * tid + 1; remT[t] = r - E - c0; }
        }
    }
    __syncthreads();
    if (tid == 0) {
        for (int t = 0; t < 4; t++) { ctrl[ST_OFF + t] = binT[t]; ctrl[ST_OFF + 4 + t] = remT[t]; }
        for (int t = 0; t < 4; t++) {
            int g = t;
            for (int q = 0; q < t; q++) if (binT[q] == binT[t]) { g = q; break; }
            ctrl[ST_OFF + 8 + t] = g;
        }
    }
}

__global__ __launch_bounds__(W_THR) void hist2_kernel(const float* __restrict__ xf,
                                                      int* __restrict__ ctrl)
{
    const int tid = threadIdx.x, bl = blockIdx.x;
    int pf[4], gp[4];
#pragma unroll
    for (int t = 0; t < 4; t++) { pf[t] = ctrl[ST_OFF + t]; gp[t] = ctrl[ST_OFF + 8 + t]; }
    float4 v = ((const float4*)xf)[(size_t)bl * W_THR + tid];
    float xv[4] = {v.x, v.y, v.z, v.w};
#pragma unroll
    for (int k = 0; k < 4; k++) {
        unsigned u = fkey(xv[k]);
        unsigned hi = u >> 21;
        int bin = (int)((u >> 10) & 2047u);
        int code = -1;
#pragma unroll
        for (int t = 0; t < 4; t++)
            if (gp[t] == t && (unsigned)pf[t] == hi) code = t * 2048 + bin;
        aggAdd(ctrl + H2_OFF, code);
    }
}

__global__ __launch_bounds__(1024) void scan2_kernel(int* __restrict__ ctrl)
{
    __shared__ int wsum[16];
    __shared__ int binT[4], remT[4];
    const int tid = threadIdx.x;
    for (int t = 0; t < 4; t++) {
        int g = ctrl[ST_OFF + 8 + t], rank = ctrl[ST_OFF + 4 + t];
        const int* h = ctrl + H2_OFF + g * 2048;
        int c0 = h[2 * tid], c1 = h[2 * tid + 1];
        int s = c0 + c1;
        int E = excl_scan1024(s, tid, wsum);
        if (rank >= E && rank < E + s) {
            if (rank < E + c0) { binT[t] = 2 * tid;     remT[t] = rank - E; }
            else               { binT[t] = 2 * tid + 1; remT[t] = rank - E - c0; }
        }
        __syncthreads();
    }
    if (tid == 0) {
        int P2n[4];
        for (int t = 0; t < 4; t++) {
            P2n[t] = (ctrl[ST_OFF + t] << 11) | binT[t];
            ctrl[ST_OFF + 12 + t] = P2n[t];
            ctrl[ST_OFF + 16 + t] = remT[t];
        }
        for (int t = 0; t < 4; t++) {
            int g = t;
            for (int q = 0; q < t; q++) if (P2n[q] == P2n[t]) { g = q; break; }
            ctrl[ST_OFF + 20 + t] = g;
        }
    }
}

__global__ __launch_bounds__(W_THR) void hist3_kernel(const float* __restrict__ xf,
                                                      int* __restrict__ ctrl)
{
    const int tid = threadIdx.x, bl = blockIdx.x;
    int pf[4], gp[4];
#pragma unroll
    for (int t = 0; t < 4; t++) { pf[t] = ctrl[ST_OFF + 12 + t]; gp[t] = ctrl[ST_OFF + 20 + t]; }
    float4 v = ((const float4*)xf)[(size_t)bl * W_THR + tid];
    float xv[4] = {v.x, v.y, v.z, v.w};
#pragma unroll
    for (int k = 0; k < 4; k++) {
        unsigned u = fkey(xv[k]);
        unsigned hi = u >> 10;
        int bin = (int)(u & 1023u);
        int code = -1;
#pragma unroll
        for (int t = 0; t < 4; t++)
            if (gp[t] == t && (unsigned)pf[t] == hi) code = t * 1024 + bin;
        aggAdd(ctrl + H3_OFF, code);
    }
}

__global__ __launch_bounds__(1024) void scan3_kernel(int* __restrict__ ctrl)
{
    __shared__ int wsum[16];
    __shared__ int binT[4];
    const int tid = threadIdx.x;
    for (int t = 0; t < 4; t++) {
        int g = ctrl[ST_OFF + 20 + t], rank = ctrl[ST_OFF + 16 + t];
        const int* h = ctrl + H3_OFF + g * 1024;
        int s = h[tid];
        int E = excl_scan1024(s, tid, wsum);
        if (rank >= E && rank < E + s) binT[t] = tid;
        __syncthreads();
    }
    if (tid == 0) {
        float* sf = (float*)(ctrl + SF_OFF);
        float v[4];
        for (int t = 0; t < 4; t++) {
            unsigned key = ((unsigned)ctrl[ST_OFF + 12 + t] << 10) | (unsigned)binT[t];
            v[t] = funkey(key);
            sf[t] = v[t];
        }
        sf[4] = v[0] + 0.15f * (v[1] - v[0]);  // p5  (idx 0.05*(B-1)=13107.15)
        sf[5] = v[2] + 0.85f * (v[3] - v[2]);  // p95 (idx 0.95*(B-1)=249035.85)
    }
}

__global__ __launch_bounds__(W_THR) void tail_kernel(const float* __restrict__ xf,
                                                     const int* __restrict__ ctrl,
                                                     float* __restrict__ ws)
{
    __shared__ float frd[4][4];
    const int tid = threadIdx.x, bl = blockIdx.x;
    const float* sf = (const float*)(ctrl + SF_OFF);
    const float p5 = sf[4], p95 = sf[5];
    float4 v = ((const float4*)xf)[(size_t)bl * W_THR + tid];
    float xv[4] = {v.x, v.y, v.z, v.w};
    float slo = 0.f, clo = 0.f, shi = 0.f, chi = 0.f;
#pragma unroll
    for (int k = 0; k < 4; k++) {
        float x = xv[k];
        if (x < p5)  { slo += x; clo += 1.f; }
        if (x > p95) { shi += x; chi += 1.f; }
    }
    slo = wred(slo); clo = wred(clo); shi = wred(shi); chi = wred(chi);
    int wid = tid >> 6, lane = tid & 63;
    if (lane == 0) { frd[wid][0] = slo; frd[wid][1] = clo; frd[wid][2] = shi; frd[wid][3] = chi; }
    __syncthreads();
    if (tid == 0) {
        float s0 = 0, s1 = 0, s2 = 0, s3 = 0;
#pragma unroll
        for (int w = 0; w < 4; w++) { s0 += frd[w][0]; s1 += frd[w][1]; s2 += frd[w][2]; s3 += frd[w][3]; }
        float* tp = ws + TAILP_OFF + bl * 4;
        tp[0] = s0; tp[1] = s1; tp[2] = s2; tp[3] = s3;
    }
}

__global__ __launch_bounds__(256) void tailfin_kernel(const float* __restrict__ ws,
                                                      float* __restrict__ out)
{
    __shared__ float frd[4][4];
    const int tid = threadIdx.x;
    const float* tp = ws + TAILP_OFF;
    float a0 = tp[tid * 4 + 0], a1 = tp[tid * 4 + 1], a2 = tp[tid * 4 + 2], a3 = tp[tid * 4 + 3];
    a0 = wred(a0); a1 = wred(a1); a2 = wred(a2); a3 = wred(a3);
    int wid = tid >> 6, lane = tid & 63;
    if (lane == 0) { frd[wid][0] = a0; frd[wid][1] = a1; frd[wid][2] = a2; frd[wid][3] = a3; }
    __syncthreads();
    if (tid == 0) {
        float Slo = 0, Clo = 0, Shi = 0, Chi = 0;
#pragma unroll
        for (int w = 0; w < 4; w++) { Slo += frd[w][0]; Clo += frd[w][1]; Shi += frd[w][2]; Chi += frd[w][3]; }
        out[2] = -Slo / fmaxf(Clo, 1.f);
        out[3] = -Shi / fmaxf(Chi, 1.f);
    }
}

// ---------------- host ----------------
extern "C" void kernel_launch(void* const* d_in, const int* in_sizes, int n_in,
                              void* d_out, int out_size, void* d_ws, size_t ws_size,
                              hipStream_t stream)
{
    const float* x_in = (const float*)d_in[0];
    const float* dW   = (const float*)d_in[1];
    const float* Wo   = (const float*)d_in[2];
    const float* bo   = (const float*)d_in[3];
    const float* Wk   = (const float*)d_in[4];
    const float* bk   = (const float*)d_in[5];
    const float* Wu0  = (const float*)d_in[6];
    const float* bu0  = (const float*)d_in[7];
    const float* W1   = (const float*)d_in[8];
    const float* b1   = (const float*)d_in[9];
    const float* W2   = (const float*)d_in[10];
    const float* b2   = (const float*)d_in[11];
    const float* W3   = (const float*)d_in[12];
    const float* b3   = (const float*)d_in[13];
    float* ws   = (float*)d_ws;
    int* ctrl   = (int*)d_ws + ICTRL;
    float* prep = ws + PREP_OFF;
    float* out  = (float*)d_out;

    zero_kernel<<<(ZTOT + 1023) / 1024, 1024, 0, stream>>>(ctrl);
    prep_kernel<<<20, 256, 0, stream>>>(Wu0, bu0, W1, b1, W2, b2, W3, b3, prep);
    sim_kernel<<<NBLK_SIM, THB_SIM, 0, stream>>>(x_in, dW, Wo, bo, Wk, bk, ws, ctrl, out, prep);
    hist1_kernel<<<H1_BLK, H1_THR, 0, stream>>>(ws, ctrl);
    scan1_kernel<<<1, 1024, 0, stream>>>(ctrl);
    hist2_kernel<<<W_BLK, W_THR, 0, stream>>>(ws, ctrl);
    scan2_kernel<<<1, 1024, 0, stream>>>(ctrl);
    hist3_kernel<<<W_BLK, W_THR, 0, stream>>>(ws, ctrl);
    scan3_kernel<<<1, 1024, 0, stream>>>(ctrl);
    tail_kernel<<<W_BLK, W_THR, 0, stream>>>(ws, ctrl, ws);
    tailfin_kernel<<<1, 256, 0, stream>>>(ws, out);
}

// Round 12
// 198.245 us; speedup vs baseline: 1.4411x; 1.3886x over previous
//
#include <hip/hip_runtime.h>
#include <math.h>

// ---------------- problem constants ----------------
#define BB 262144
#define NST 20
#define RHc 0.006f            // R*H
#define BHc 0.01f             // B_DRIFT*H
#define SIGc 0.2f
#define CURTc 0.005f
#define DISCf 0.8869204367171575f   // exp(-0.12)

// ---------------- launch geometry ----------------
#define P 4                    // paths per thread (amortizes LDS weight reads)
#define THB 256
#define NBLK_SIM 256           // B / (THB*P)
#define CH 65536               // path chunk stride = BB / P
#define H1_BLK 16
#define H1_THR 1024
#define W_BLK 256
#define W_THR 256

// ---------------- workspace layout (floats from ws base unless noted) ----------------
#define SIMP_OFF  BB                          // float[NBLK_SIM*5]
#define TAILP_OFF (SIMP_OFF + NBLK_SIM * 5)   // float[W_BLK*4]
#define ICTRL     (TAILP_OFF + W_BLK * 4)     // int region base
// ctrl ints:
#define H2_OFF 0                      // 4*2048
#define H3_OFF 8192                   // 4*1024
#define CNT_OFF 12288                 // sim last-block counter
#define ST_OFF  12296                 // P1[4] R1[4] G2[4] P2[4] R2[4] G3[4]
#define SF_OFF  12320                 // floats: v[4], p5, p95
#define ZTOT    12289                 // ints zeroed per call (H2,H3,CNT)
#define H1R_OFF 12352                 // 16 rows x 2048 ints
// extent: ICTRL + 12352 + 32768 = BB + 47424 = 309,568 floats (< proven 318,528)

// ---------------- helpers ----------------
__device__ __forceinline__ unsigned fkey(float f) {
    unsigned u = __float_as_uint(f);
    return (u & 0x80000000u) ? ~u : (u | 0x80000000u);
}
__device__ __forceinline__ float funkey(unsigned k) {
    return __uint_as_float((k & 0x80000000u) ? (k ^ 0x80000000u) : ~k);
}
__device__ __forceinline__ float wred(float v) {
#pragma unroll
    for (int o = 32; o > 0; o >>= 1) v += __shfl_down(v, o);
    return v;
}

__global__ void zero_kernel(int* __restrict__ ctrl) {
    int i = blockIdx.x * blockDim.x + threadIdx.x;
    if (i < ZTOT) ctrl[i] = 0;
}

// 20-wide FMA accumulate / dot macros (all indices compile-time after unroll)
#define ACC20(P_) do { \
  h2[P_][0]=fmaf(hv,wa.x,h2[P_][0]);  h2[P_][1]=fmaf(hv,wa.y,h2[P_][1]); \
  h2[P_][2]=fmaf(hv,wa.z,h2[P_][2]);  h2[P_][3]=fmaf(hv,wa.w,h2[P_][3]); \
  h2[P_][4]=fmaf(hv,wb2.x,h2[P_][4]); h2[P_][5]=fmaf(hv,wb2.y,h2[P_][5]); \
  h2[P_][6]=fmaf(hv,wb2.z,h2[P_][6]); h2[P_][7]=fmaf(hv,wb2.w,h2[P_][7]); \
  h2[P_][8]=fmaf(hv,wc2.x,h2[P_][8]); h2[P_][9]=fmaf(hv,wc2.y,h2[P_][9]); \
  h2[P_][10]=fmaf(hv,wc2.z,h2[P_][10]); h2[P_][11]=fmaf(hv,wc2.w,h2[P_][11]); \
  h2[P_][12]=fmaf(hv,wd2.x,h2[P_][12]); h2[P_][13]=fmaf(hv,wd2.y,h2[P_][13]); \
  h2[P_][14]=fmaf(hv,wd2.z,h2[P_][14]); h2[P_][15]=fmaf(hv,wd2.w,h2[P_][15]); \
  h2[P_][16]=fmaf(hv,we2.x,h2[P_][16]); h2[P_][17]=fmaf(hv,we2.y,h2[P_][17]); \
  h2[P_][18]=fmaf(hv,we2.z,h2[P_][18]); h2[P_][19]=fmaf(hv,we2.w,h2[P_][19]); \
} while (0)

#define DOT20(P_) do { \
  a=fmaf(h2[P_][0],wa.x,a);  a=fmaf(h2[P_][1],wa.y,a);  a=fmaf(h2[P_][2],wa.z,a);  a=fmaf(h2[P_][3],wa.w,a); \
  a=fmaf(h2[P_][4],wb2.x,a); a=fmaf(h2[P_][5],wb2.y,a); a=fmaf(h2[P_][6],wb2.z,a); a=fmaf(h2[P_][7],wb2.w,a); \
  a=fmaf(h2[P_][8],wc2.x,a); a=fmaf(h2[P_][9],wc2.y,a); a=fmaf(h2[P_][10],wc2.z,a); a=fmaf(h2[P_][11],wc2.w,a); \
  a=fmaf(h2[P_][12],wd2.x,a); a=fmaf(h2[P_][13],wd2.y,a); a=fmaf(h2[P_][14],wd2.z,a); a=fmaf(h2[P_][15],wd2.w,a); \
  a=fmaf(h2[P_][16],we2.x,a); a=fmaf(h2[P_][17],we2.y,a); a=fmaf(h2[P_][18],we2.z,a); a=fmaf(h2[P_][19],we2.w,a); \
} while (0)

// ---------------- main simulation: P=4 paths/thread, fp32 weights in LDS (R2-proven) ----------------
__global__ __launch_bounds__(THB, 1) void sim_kernel(
    const float* __restrict__ x_in, const float* __restrict__ dW,
    const float* __restrict__ Wo, const float* __restrict__ bo,
    const float* __restrict__ Wk, const float* __restrict__ bk,
    const float* __restrict__ Wu0, const float* __restrict__ bu0,
    const float* __restrict__ W1, const float* __restrict__ b1,
    const float* __restrict__ W2, const float* __restrict__ b2,
    const float* __restrict__ W3, const float* __restrict__ b3,
    float* __restrict__ ws, int* __restrict__ ctrl, float* __restrict__ out)
{
    // LDS per step s (stride 568): [0,20) W1row | [20,40) b1 | [40,440) W2 row-major |
    // [440,460) b2 | [460,560) W3T (5 rows x 20) | [560,565) b3
    __shared__ float L[10844];
    __shared__ float red[4][5];
    __shared__ int lastF;
    const int tid = threadIdx.x;

    for (int t = tid; t < 19 * 20; t += THB) {
        int s = t / 20, j = t % 20;
        L[s * 568 + j]       = W1[t];
        L[s * 568 + 20 + j]  = b1[t];
        L[s * 568 + 440 + j] = b2[t];
    }
    for (int t = tid; t < 19 * 400; t += THB) {
        int s = t / 400, r = t % 400;
        L[s * 568 + 40 + r] = W2[t];
    }
    for (int t = tid; t < 19 * 100; t += THB) {
        int s = t / 100, r = t % 100, i = r / 5, k = r % 5;
        L[s * 568 + 460 + k * 20 + i] = W3[t];
    }
    for (int t = tid; t < 19 * 5; t += THB) {
        int s = t / 5, k = t % 5;
        L[s * 568 + 560 + k] = b3[t];
    }
    if (tid < 11) { L[10792 + tid] = Wo[tid]; L[10803 + tid] = bo[tid]; }
    if (tid < 10) { L[10814 + tid] = Wk[tid]; L[10824 + tid] = bk[tid]; }
    if (tid < 5)  { L[10834 + tid] = Wu0[tid]; L[10839 + tid] = bu0[tid]; }
    __syncthreads();

    const int b0 = blockIdx.x * THB + tid;

    float x[P], K0[P], smv = 0.f;
    float alpha[P][5], S[P][5], SQ[P][5], dN[P][5], Nm1[P][5], dwb[P][5];

#pragma unroll
    for (int p = 0; p < P; p++) {
        int b = b0 + p * CH;
        float xx = x_in[b];
        x[p] = xx;
        float z[11], zm = -1e30f;
#pragma unroll
        for (int j = 0; j < 11; j++) {
            z[j] = fmaf(xx, L[10792 + j], L[10803 + j]);
            zm = fmaxf(zm, z[j]);
        }
        float se = 0.f;
#pragma unroll
        for (int j = 0; j < 11; j++) se += __expf(z[j] - zm);
        smv += __expf(z[10] - zm) / se;
        K0[p] = 1.f + 0.25f * tanhf(fmaf(xx, L[10814], L[10824]));
#pragma unroll
        for (int d = 0; d < 5; d++) {
            alpha[p][d] = fmaf(xx, L[10834 + d], L[10839 + d]);
            S[p][d] = 1.f; SQ[p][d] = 1.f; dN[p][d] = 0.f;
            Nm1[p][d] = alpha[p][d];
        }
        const float* pw = dW + (size_t)b * 5;
#pragma unroll
        for (int d = 0; d < 5; d++) dwb[p][d] = pw[d];
    }

#pragma unroll 1
    for (int n = 1; n <= NST; n++) {
        float dwc[P][5];
#pragma unroll
        for (int p = 0; p < P; p++)
#pragma unroll
            for (int d = 0; d < 5; d++) dwc[p][d] = dwb[p][d];
        if (n < NST) {  // prefetch next step's noise (hides under MLP)
#pragma unroll
            for (int p = 0; p < P; p++) {
                const float* pw = dW + ((size_t)n * BB + b0 + p * CH) * 5;
#pragma unroll
                for (int d = 0; d < 5; d++) dwb[p][d] = pw[d];
            }
        }
        // wealth / price Euler step
#pragma unroll
        for (int p = 0; p < P; p++) {
            float usum = 0.f, du = 0.f;
#pragma unroll
            for (int d = 0; d < 5; d++) {
                float u = alpha[p][d];
                float Np = u * __builtin_amdgcn_rcpf(S[p][d]);
                dN[p][d] += fabsf(Np - Nm1[p][d]);
                Nm1[p][d] = Np;
                usum += u;
                du = fmaf(u, fmaf(SIGc, dwc[p][d], BHc), du);
            }
            x[p] = fmaf(x[p] - usum, RHc, x[p]) + du;
#pragma unroll
            for (int d = 0; d < 5; d++) {
                float g = SIGc * dwc[p][d];
                S[p][d]  *= (1.f + BHc + g);
                SQ[p][d] *= (1.f + RHc + g);
            }
        }
        if (n < NST) {
            const float* Ls = L + (n - 1) * 568;
            float h2[P][20];
#pragma unroll
            for (int j4 = 0; j4 < 5; j4++) {
                float4 c = *(const float4*)(Ls + 440 + j4 * 4);
#pragma unroll
                for (int p = 0; p < P; p++) {
                    h2[p][j4 * 4 + 0] = c.x; h2[p][j4 * 4 + 1] = c.y;
                    h2[p][j4 * 4 + 2] = c.z; h2[p][j4 * 4 + 3] = c.w;
                }
            }
#pragma unroll 1
            for (int i4 = 0; i4 < 5; i4++) {
                float4 w1c = *(const float4*)(Ls + i4 * 4);
                float4 c1c = *(const float4*)(Ls + 20 + i4 * 4);
                const float* wr0 = Ls + 40 + i4 * 80;
#pragma unroll
                for (int ii = 0; ii < 4; ii++) {
                    const float* wr = wr0 + ii * 20;
                    float4 wa  = *(const float4*)(wr + 0);
                    float4 wb2 = *(const float4*)(wr + 4);
                    float4 wc2 = *(const float4*)(wr + 8);
                    float4 wd2 = *(const float4*)(wr + 12);
                    float4 we2 = *(const float4*)(wr + 16);
                    float wv = (ii == 0) ? w1c.x : (ii == 1) ? w1c.y : (ii == 2) ? w1c.z : w1c.w;
                    float cv = (ii == 0) ? c1c.x : (ii == 1) ? c1c.y : (ii == 2) ? c1c.z : c1c.w;
#pragma unroll
                    for (int p = 0; p < P; p++) {
                        float hv = fmaxf(fmaf(x[p], wv, cv), 0.f);
                        ACC20(p);
                    }
                }
            }
#pragma unroll
            for (int p = 0; p < P; p++)
#pragma unroll
                for (int j = 0; j < 20; j++) h2[p][j] = fmaxf(h2[p][j], 0.f);
#pragma unroll
            for (int k = 0; k < 5; k++) {
                const float* wr = Ls + 460 + k * 20;
                float4 wa  = *(const float4*)(wr + 0);
                float4 wb2 = *(const float4*)(wr + 4);
                float4 wc2 = *(const float4*)(wr + 8);
                float4 wd2 = *(const float4*)(wr + 12);
                float4 we2 = *(const float4*)(wr + 16);
                float bb = Ls[560 + k];
#pragma unroll
                for (int p = 0; p < P; p++) {
                    float a = bb;
                    DOT20(p);
                    alpha[p][k] = a;
                }
            }
        }
    }

    float v0 = 0.f, v1 = 0.f, v2 = 0.f, v3 = 0.f, v4 = smv;
#pragma unroll
    for (int p = 0; p < P; p++) {
        float dNs = dN[p][0] + dN[p][1] + dN[p][2] + dN[p][3] + dN[p][4];
        float xx = fmaf(-CURTc, dNs, x[p]);
        ws[b0 + p * CH] = xx;
        v0 += xx; v1 += xx * xx;
        v2 += fmaxf(S[p][0]  - K0[p], 0.f);
        v3 += fmaxf(SQ[p][0] - K0[p], 0.f);
    }

    v0 = wred(v0); v1 = wred(v1); v2 = wred(v2); v3 = wred(v3); v4 = wred(v4);
    int wid = tid >> 6, lane = tid & 63;
    if (lane == 0) { red[wid][0] = v0; red[wid][1] = v1; red[wid][2] = v2; red[wid][3] = v3; red[wid][4] = v4; }
    __syncthreads();
    if (tid == 0) {
        float s0 = 0, s1 = 0, s2 = 0, s3 = 0, s4 = 0;
#pragma unroll
        for (int w = 0; w < 4; w++) { s0 += red[w][0]; s1 += red[w][1]; s2 += red[w][2]; s3 += red[w][3]; s4 += red[w][4]; }
        float* part = ws + SIMP_OFF + blockIdx.x * 5;
        part[0] = s0; part[1] = s1; part[2] = s2; part[3] = s3; part[4] = s4;
    }
    __threadfence();
    if (tid == 0) lastF = (atomicAdd(&ctrl[CNT_OFF], 1) == NBLK_SIM - 1);
    __syncthreads();
    if (!lastF) return;
    __threadfence();

    // final deterministic reduce of 256 partial rows (one per thread)
    const float* part = ws + SIMP_OFF;
    float a0 = part[tid * 5 + 0], a1 = part[tid * 5 + 1], a2 = part[tid * 5 + 2],
          a3 = part[tid * 5 + 3], a4 = part[tid * 5 + 4];
    a0 = wred(a0); a1 = wred(a1); a2 = wred(a2); a3 = wred(a3); a4 = wred(a4);
    if (lane == 0) { red[wid][0] = a0; red[wid][1] = a1; red[wid][2] = a2; red[wid][3] = a3; red[wid][4] = a4; }
    __syncthreads();
    if (tid == 0) {
        float Sx = 0, Sx2 = 0, SP = 0, SQs = 0, Ssm = 0;
#pragma unroll
        for (int w = 0; w < 4; w++) { Sx += red[w][0]; Sx2 += red[w][1]; SP += red[w][2]; SQs += red[w][3]; Ssm += red[w][4]; }
        float invB = 1.f / (float)BB;
        float meanx = Sx * invB;
        out[0] = -meanx;
        out[1] = Sx2 * invB - meanx * meanx;
        out[4] = (SP * invB) / (DISCf * (SQs * invB) + 1e-8f);
        out[5] = 1.f + 0.25f * tanhf(fmaf(x_in[0], Wk[1], bk[1]));
        out[6] = Ssm * invB;
    }
}

// ---------------- select helpers ----------------
__device__ __forceinline__ void aggAdd(int* h, int code) {
    bool act = (code >= 0);
    unsigned long long mask = __ballot(act);
    while (mask) {
        int leader = __ffsll((unsigned long long)mask) - 1;
        int lc = __shfl(code, leader);
        unsigned long long mm = __ballot(act && code == lc);
        if ((threadIdx.x & 63) == leader) atomicAdd(&h[lc], (int)__popcll(mm));
        mask &= ~mm;
    }
}

__device__ int excl_scan1024(int v, int tid, int* wsum) {
    __syncthreads();
    int lane = tid & 63, wid = tid >> 6;
    int inc = v;
#pragma unroll
    for (int o = 1; o < 64; o <<= 1) { int u = __shfl_up(inc, o); if (lane >= o) inc += u; }
    if (lane == 63) wsum[wid] = inc;
    __syncthreads();
    if (tid < 16) {
        int wv = wsum[tid], winc = wv;
#pragma unroll
        for (int o = 1; o < 16; o <<= 1) { int u = __shfl_up(winc, o); if (tid >= o) winc += u; }
        wsum[tid] = winc - wv;
    }
    __syncthreads();
    return wsum[wid] + inc - v;
}

__global__ __launch_bounds__(H1_THR) void hist1_kernel(const float* __restrict__ xf,
                                                       int* __restrict__ ctrl)
{
    __shared__ int lh[2048];
    const int tid = threadIdx.x, bl = blockIdx.x;
    for (int i = tid; i < 2048; i += H1_THR) lh[i] = 0;
    __syncthreads();
    const float4* xf4 = (const float4*)xf;
#pragma unroll
    for (int w = 0; w < 4; w++) {
        float4 v = xf4[(size_t)bl * 4096 + w * 1024 + tid];
        aggAdd(lh, (int)(fkey(v.x) >> 21));
        aggAdd(lh, (int)(fkey(v.y) >> 21));
        aggAdd(lh, (int)(fkey(v.z) >> 21));
        aggAdd(lh, (int)(fkey(v.w) >> 21));
    }
    __syncthreads();
    int* row = ctrl + H1R_OFF + bl * 2048;
    for (int i = tid; i < 2048; i += H1_THR) row[i] = lh[i];
}

__global__ __launch_bounds__(1024) void scan1_kernel(int* __restrict__ ctrl)
{
    __shared__ int wsum[16];
    __shared__ int binT[4], remT[4];
    const int tid = threadIdx.x;
    const int* rows = ctrl + H1R_OFF;
    int c0 = 0, c1 = 0;
    for (int r = 0; r < H1_BLK; r++) {
        c0 += rows[r * 2048 + 2 * tid];
        c1 += rows[r * 2048 + 2 * tid + 1];
    }
    int s = c0 + c1;
    int E = excl_scan1024(s, tid, wsum);
    const int RK[4] = {13107, 13108, 249035, 249036};
#pragma unroll
    for (int t = 0; t < 4; t++) {
        int r = RK[t];
        if (r >= E && r < E + s) {
            if (r < E + c0) { binT[t] = 2 * tid;     remT[t] = r - E; }
            else            { binT[t] = 2 * tid + 1; remT[t] = r - E - c0; }
        }
    }
    __syncthreads();
    if (tid == 0) {
        for (int t = 0; t < 4; t++) { ctrl[ST_OFF + t] = binT[t]; ctrl[ST_OFF + 4 + t] = remT[t]; }
        for (int t = 0; t < 4; t++) {
            int g = t;
            for (int q = 0; q < t; q++) if (binT[q] == binT[t]) { g = q; break; }
            ctrl[ST_OFF + 8 + t] = g;
        }
    }
}

__global__ __launch_bounds__(W_THR) void hist2_kernel(const float* __restrict__ xf,
                                                      int* __restrict__ ctrl)
{
    const int tid = threadIdx.x, bl = blockIdx.x;
    int pf[4], gp[4];
#pragma unroll
    for (int t = 0; t < 4; t++) { pf[t] = ctrl[ST_OFF + t]; gp[t] = ctrl[ST_OFF + 8 + t]; }
    float4 v = ((const float4*)xf)[(size_t)bl * W_THR + tid];
    float xv[4] = {v.x, v.y, v.z, v.w};
#pragma unroll
    for (int k = 0; k < 4; k++) {
        unsigned u = fkey(xv[k]);
        unsigned hi = u >> 21;
        int bin = (int)((u >> 10) & 2047u);
        int code = -1;
#pragma unroll
        for (int t = 0; t < 4; t++)
            if (gp[t] == t && (unsigned)pf[t] == hi) code = t * 2048 + bin;
        aggAdd(ctrl + H2_OFF, code);
    }
}

__global__ __launch_bounds__(1024) void scan2_kernel(int* __restrict__ ctrl)
{
    __shared__ int wsum[16];
    __shared__ int binT[4], remT[4];
    const int tid = threadIdx.x;
    for (int t = 0; t < 4; t++) {
        int g = ctrl[ST_OFF + 8 + t], rank = ctrl[ST_OFF + 4 + t];
        const int* h = ctrl + H2_OFF + g * 2048;
        int c0 = h[2 * tid], c1 = h[2 * tid + 1];
        int s = c0 + c1;
        int E = excl_scan1024(s, tid, wsum);
        if (rank >= E && rank < E + s) {
            if (rank < E + c0) { binT[t] = 2 * tid;     remT[t] = rank - E; }
            else               { binT[t] = 2 * tid + 1; remT[t] = rank - E - c0; }
        }
        __syncthreads();
    }
    if (tid == 0) {
        int P2n[4];
        for (int t = 0; t < 4; t++) {
            P2n[t] = (ctrl[ST_OFF + t] << 11) | binT[t];
            ctrl[ST_OFF + 12 + t] = P2n[t];
            ctrl[ST_OFF + 16 + t] = remT[t];
        }
        for (int t = 0; t < 4; t++) {
            int g = t;
            for (int q = 0; q < t; q++) if (P2n[q] == P2n[t]) { g = q; break; }
            ctrl[ST_OFF + 20 + t] = g;
        }
    }
}

__global__ __launch_bounds__(W_THR) void hist3_kernel(const float* __restrict__ xf,
                                                      int* __restrict__ ctrl)
{
    const int tid = threadIdx.x, bl = blockIdx.x;
    int pf[4], gp[4];
#pragma unroll
    for (int t = 0; t < 4; t++) { pf[t] = ctrl[ST_OFF + 12 + t]; gp[t] = ctrl[ST_OFF + 20 + t]; }
    float4 v = ((const float4*)xf)[(size_t)bl * W_THR + tid];
    float xv[4] = {v.x, v.y, v.z, v.w};
#pragma unroll
    for (int k = 0; k < 4; k++) {
        unsigned u = fkey(xv[k]);
        unsigned hi = u >> 10;
        int bin = (int)(u & 1023u);
        int code = -1;
#pragma unroll
        for (int t = 0; t < 4; t++)
            if (gp[t] == t && (unsigned)pf[t] == hi) code = t * 1024 + bin;
        aggAdd(ctrl + H3_OFF, code);
    }
}

__global__ __launch_bounds__(1024) void scan3_kernel(int* __restrict__ ctrl)
{
    __shared__ int wsum[16];
    __shared__ int binT[4];
    const int tid = threadIdx.x;
    for (int t = 0; t < 4; t++) {
        int g = ctrl[ST_OFF + 20 + t], rank = ctrl[ST_OFF + 16 + t];
        const int* h = ctrl + H3_OFF + g * 1024;
        int s = h[tid];
        int E = excl_scan1024(s, tid, wsum);
        if (rank >= E && rank < E + s) binT[t] = tid;
        __syncthreads();
    }
    if (tid == 0) {
        float* sf = (float*)(ctrl + SF_OFF);
        float v[4];
        for (int t = 0; t < 4; t++) {
            unsigned key = ((unsigned)ctrl[ST_OFF + 12 + t] << 10) | (unsigned)binT[t];
            v[t] = funkey(key);
            sf[t] = v[t];
        }
        sf[4] = v[0] + 0.15f * (v[1] - v[0]);  // p5  (idx 0.05*(B-1)=13107.15)
        sf[5] = v[2] + 0.85f * (v[3] - v[2]);  // p95 (idx 0.95*(B-1)=249035.85)
    }
}

__global__ __launch_bounds__(W_THR) void tail_kernel(const float* __restrict__ xf,
                                                     const int* __restrict__ ctrl,
                                                     float* __restrict__ ws)
{
    __shared__ float frd[4][4];
    const int tid = threadIdx.x, bl = blockIdx.x;
    const float* sf = (const float*)(ctrl + SF_OFF);
    const float p5 = sf[4], p95 = sf[5];
    float4 v = ((const float4*)xf)[(size_t)bl * W_THR + tid];
    float xv[4] = {v.x, v.y, v.z, v.w};
    float slo = 0.f, clo = 0.f, shi = 0.f, chi = 0.f;
#pragma unroll
    for (int k = 0; k < 4; k++) {
        float x = xv[k];
        if (x < p5)  { slo += x; clo += 1.f; }
        if (x > p95) { shi += x; chi += 1.f; }
    }
    slo = wred(slo); clo = wred(clo); shi = wred(shi); chi = wred(chi);
    int wid = tid >> 6, lane = tid & 63;
    if (lane == 0) { frd[wid][0] = slo; frd[wid][1] = clo; frd[wid][2] = shi; frd[wid][3] = chi; }
    __syncthreads();
    if (tid == 0) {
        float s0 = 0, s1 = 0, s2 = 0, s3 = 0;
#pragma unroll
        for (int w = 0; w < 4; w++) { s0 += frd[w][0]; s1 += frd[w][1]; s2 += frd[w][2]; s3 += frd[w][3]; }
        float* tp = ws + TAILP_OFF + bl * 4;
        tp[0] = s0; tp[1] = s1; tp[2] = s2; tp[3] = s3;
    }
}

__global__ __launch_bounds__(256) void tailfin_kernel(const float* __restrict__ ws,
                                                      float* __restrict__ out)
{
    __shared__ float frd[4][4];
    const int tid = threadIdx.x;
    const float* tp = ws + TAILP_OFF;
    float a0 = tp[tid * 4 + 0], a1 = tp[tid * 4 + 1], a2 = tp[tid * 4 + 2], a3 = tp[tid * 4 + 3];
    a0 = wred(a0); a1 = wred(a1); a2 = wred(a2); a3 = wred(a3);
    int wid = tid >> 6, lane = tid & 63;
    if (lane == 0) { frd[wid][0] = a0; frd[wid][1] = a1; frd[wid][2] = a2; frd[wid][3] = a3; }
    __syncthreads();
    if (tid == 0) {
        float Slo = 0, Clo = 0, Shi = 0, Chi = 0;
#pragma unroll
        for (int w = 0; w < 4; w++) { Slo += frd[w][0]; Clo += frd[w][1]; Shi += frd[w][2]; Chi += frd[w][3]; }
        out[2] = -Slo / fmaxf(Clo, 1.f);
        out[3] = -Shi / fmaxf(Chi, 1.f);
    }
}

// ---------------- host ----------------
extern "C" void kernel_launch(void* const* d_in, const int* in_sizes, int n_in,
                              void* d_out, int out_size, void* d_ws, size_t ws_size,
                              hipStream_t stream)
{
    const float* x_in = (const float*)d_in[0];
    const float* dW   = (const float*)d_in[1];
    const float* Wo   = (const float*)d_in[2];
    const float* bo   = (const float*)d_in[3];
    const float* Wk   = (const float*)d_in[4];
    const float* bk   = (const float*)d_in[5];
    const float* Wu0  = (const float*)d_in[6];
    const float* bu0  = (const float*)d_in[7];
    const float* W1   = (const float*)d_in[8];
    const float* b1   = (const float*)d_in[9];
    const float* W2   = (const float*)d_in[10];
    const float* b2   = (const float*)d_in[11];
    const float* W3   = (const float*)d_in[12];
    const float* b3   = (const float*)d_in[13];
    float* ws  = (float*)d_ws;
    int* ctrl  = (int*)d_ws + ICTRL;
    float* out = (float*)d_out;

    zero_kernel<<<(ZTOT + 1023) / 1024, 1024, 0, stream>>>(ctrl);
    sim_kernel<<<NBLK_SIM, THB, 0, stream>>>(x_in, dW, Wo, bo, Wk, bk, Wu0, bu0,
                                             W1, b1, W2, b2, W3, b3, ws, ctrl, out);
    hist1_kernel<<<H1_BLK, H1_THR, 0, stream>>>(ws, ctrl);
    scan1_kernel<<<1, 1024, 0, stream>>>(ctrl);
    hist2_kernel<<<W_BLK, W_THR, 0, stream>>>(ws, ctrl);
    scan2_kernel<<<1, 1024, 0, stream>>>(ctrl);
    hist3_kernel<<<W_BLK, W_THR, 0, stream>>>(ws, ctrl);
    scan3_kernel<<<1, 1024, 0, stream>>>(ctrl);
    tail_kernel<<<W_BLK, W_THR, 0, stream>>>(ws, ctrl, ws);
    tailfin_kernel<<<1, 256, 0, stream>>>(ws, out);
}